// Round 7
// baseline (408.590 us; speedup 1.0000x reference)
//
#include <hip/hip_runtime.h>
#include <hip/hip_bf16.h>

// RGCN layer, MI355X — round 7.
// r6 post-mortem: super-tile barriers regressed conv (82->100us); pipeline
// fusion helped the tail (301->268us). This round: conv-v3 — all-register,
// barrier-free. No LDS at all: B frags (L2-resident W) and A frags (node_bf
// gathers) load straight to VGPRs; meta via lane loads + shfl. 64-edge tiles,
// 10240 independent blocks, ~148 VGPR @ launch_bounds(256,3).

#define N_NODES 20000
#define E_EDGES 640000
#define R_REL   65
#define TM      64
#define MAX_TILES 10240
#define SCAT_CH 2560

typedef __attribute__((ext_vector_type(8))) short bf16x8;
typedef __attribute__((ext_vector_type(4))) float f32x4;
typedef __attribute__((ext_vector_type(4))) unsigned int u32x4;
typedef __attribute__((ext_vector_type(2))) unsigned int u32x2;

__device__ __forceinline__ unsigned short f2bf(float x) {
    union { float f; unsigned int u; } c; c.f = x;
    unsigned int b = c.u + 0x7fffu + ((c.u >> 16) & 1u);   // RTNE
    return (unsigned short)(b >> 16);
}
__device__ __forceinline__ float bf2f_lo(unsigned int u) {
    union { unsigned int u; float f; } c; c.u = u << 16; return c.f;
}
__device__ __forceinline__ float bf2f_hi(unsigned int u) {
    union { unsigned int u; float f; } c; c.u = u & 0xffff0000u; return c.f;
}
__device__ __forceinline__ void async16(const void* g, void* l) {
    __builtin_amdgcn_global_load_lds(
        (const __attribute__((address_space(1))) unsigned int*)g,
        (__attribute__((address_space(3))) unsigned int*)l, 16, 0, 0);
}
__device__ __forceinline__ int unperm(int p) {      // permuted pos -> true col
    return (p & 64) + ((p & 3) << 4) + ((p >> 2) & 15);
}

// ---------------- K0a: W32[r, i*128+o] = sum_b comp[r,b]*basis[b,i,o] ------
__global__ void k_basis_gemm(const float* __restrict__ comp,
                             const float* __restrict__ basis,
                             float* __restrict__ W32) {
    __shared__ float lc[16 * 65];
    int r0 = blockIdx.y * 16;
    int col = blockIdx.x * 256 + threadIdx.x;
    for (int j = threadIdx.x; j < 16 * 65; j += 256) {
        int rr = r0 + j / 65;
        lc[j] = (rr < R_REL) ? comp[rr * 65 + (j % 65)] : 0.f;
    }
    __syncthreads();
    float acc[16];
#pragma unroll
    for (int j = 0; j < 16; ++j) acc[j] = 0.f;
    for (int k = 0; k < 65; ++k) {
        float v = basis[k * 16384 + col];
#pragma unroll
        for (int j = 0; j < 16; ++j) acc[j] += lc[j * 65 + k] * v;
    }
#pragma unroll
    for (int j = 0; j < 16; ++j) {
        int rr = r0 + j;
        if (rr < R_REL) W32[rr * 16384 + col] = acc[j];
    }
}

// ---------------- K0b: transpose fp32 [i][o] -> bf16 [o][i] ----------------
__global__ void k_transpose_bf16(const float* __restrict__ src,
                                 unsigned short* __restrict__ dst) {
    __shared__ float tile[64][65];
    int b = blockIdx.x;
    int mat = b >> 2, ot = (b >> 1) & 1, itl = b & 1;
    const float* s = src + (size_t)mat * 16384;
    unsigned short* d = dst + (size_t)mat * 16384;
    int tx = threadIdx.x & 63, ty = threadIdx.x >> 6;
    for (int it = 0; it < 16; ++it) {
        int i = ty + it * 4;
        tile[i][tx] = s[(itl * 64 + i) * 128 + ot * 64 + tx];
    }
    __syncthreads();
    for (int it = 0; it < 16; ++it) {
        int o = ty + it * 4;
        d[(ot * 64 + o) * 128 + itl * 64 + tx] = f2bf(tile[tx][o]);
    }
}

// ---------------- K1a: etype histogram + dst histogram, one pass -----------
__global__ void k_hist2(const int* __restrict__ et, const int* __restrict__ dstA,
                        int* __restrict__ ghist, int* __restrict__ gh2) {
    __shared__ int lh[R_REL];
    if (threadIdx.x < R_REL) lh[threadIdx.x] = 0;
    __syncthreads();
    for (int i = blockIdx.x * 256 + threadIdx.x; i < E_EDGES; i += gridDim.x * 256) {
        atomicAdd(&lh[et[i]], 1);
        atomicAdd(&gh2[dstA[i]], 1);
    }
    __syncthreads();
    if (threadIdx.x < R_REL) atomicAdd(&ghist[threadIdx.x], lh[threadIdx.x]);
}

// ---------------- K1b: per-block partial sums of gh2 -----------------------
__global__ void k_scanA(const int* __restrict__ gh2, int* __restrict__ bsum) {
    int i = blockIdx.x * 256 + threadIdx.x;
    int v = (i < N_NODES) ? gh2[i] : 0;
    __shared__ int red[256];
    red[threadIdx.x] = v;
    __syncthreads();
    for (int off = 128; off > 0; off >>= 1) {
        if (threadIdx.x < off) red[threadIdx.x] += red[threadIdx.x + off];
        __syncthreads();
    }
    if (threadIdx.x == 0) bsum[blockIdx.x] = red[0];
}

// ---------------- K1c: small scans: bsum[80], ghist->base, tile descs ------
__global__ void k_scan_small(const int* __restrict__ ghist, int* __restrict__ bsum,
                             int* __restrict__ cnt, int* __restrict__ ntiles_p,
                             int* __restrict__ tile_rel, int* __restrict__ tile_start,
                             int* __restrict__ tile_len) {
    __shared__ int base[R_REL + 1], tbase[R_REL + 1];
    int t = threadIdx.x, w = t >> 6, lane = t & 63;
    if (w == 0) {                                   // exclusive scan bsum[80]
        int v0 = bsum[lane];
        int x = v0;
#pragma unroll
        for (int off = 1; off < 64; off <<= 1) {
            int y = __shfl_up(x, off);
            if (lane >= off) x += y;
        }
        int tot0 = __shfl(x, 63);
        int v1 = (lane < 16) ? bsum[64 + lane] : 0;
        int x1 = v1;
#pragma unroll
        for (int off = 1; off < 16; off <<= 1) {
            int y = __shfl_up(x1, off);
            if (lane >= off) x1 += y;
        }
        bsum[lane] = x - v0;
        if (lane < 16) bsum[64 + lane] = (x1 - v1) + tot0;
    } else if (w == 1) {                            // exclusive scan ghist[65]
        int v = (lane < 64) ? ghist[lane] : 0;
        int x = v;
#pragma unroll
        for (int off = 1; off < 64; off <<= 1) {
            int y = __shfl_up(x, off);
            if (lane >= off) x += y;
        }
        base[lane] = x - v;
        if (lane == 63) {
            base[64] = x;
            base[65] = x + ghist[64];
        }
    }
    __syncthreads();
    if (t == 0) {
        int tb = 0;
        for (int r = 0; r < R_REL; ++r) {
            tbase[r] = tb;
            int h = base[r + 1] - base[r];
            tb += (h + TM - 1) / TM;
        }
        *ntiles_p = tb;
    }
    __syncthreads();
    if (t < R_REL) {
        cnt[t] = base[t];
        int s = base[t], e = base[t + 1], j = tbase[t];
        while (s < e) {
            int len = min(TM, e - s);
            tile_rel[j] = t; tile_start[j] = s; tile_len[j] = len;
            ++j; s += len;
        }
    }
}

// ---------------- K1d: block scan -> cnt2 (dst bases) + seg ----------------
__global__ void k_scanC(const int* __restrict__ gh2, const int* __restrict__ bsum,
                        int* __restrict__ cnt2, int* __restrict__ seg) {
    int i = blockIdx.x * 256 + threadIdx.x;
    int v = (i < N_NODES) ? gh2[i] : 0;
    __shared__ int red[256];
    red[threadIdx.x] = v;
    __syncthreads();
    for (int off = 1; off < 256; off <<= 1) {
        int x = (threadIdx.x >= off) ? red[threadIdx.x - off] : 0;
        __syncthreads();
        red[threadIdx.x] += x;
        __syncthreads();
    }
    int excl = red[threadIdx.x] - v + bsum[blockIdx.x];
    if (i < N_NODES) {
        cnt2[i] = excl;
        seg[i] = excl;
        if (i == N_NODES - 1) seg[N_NODES] = excl + v;   // == E
    }
}

// ---------------- K1e: rel scatter + dst-position assignment ---------------
__global__ void k_scatter2(const int* __restrict__ et, const int* __restrict__ srcA,
                           const int* __restrict__ dstA, const float* __restrict__ norm,
                           int* __restrict__ cnt, int* __restrict__ cnt2,
                           int* __restrict__ srcp, float* __restrict__ normp,
                           int* __restrict__ inv2) {
    __shared__ int lh[R_REL], lbase[R_REL];
    int c0 = blockIdx.x * SCAT_CH;
    int cend = min(c0 + SCAT_CH, E_EDGES);
    if (threadIdx.x < R_REL) lh[threadIdx.x] = 0;
    __syncthreads();
    for (int i = c0 + threadIdx.x; i < cend; i += 256) atomicAdd(&lh[et[i]], 1);
    __syncthreads();
    if (threadIdx.x < R_REL && lh[threadIdx.x] > 0)
        lbase[threadIdx.x] = atomicAdd(&cnt[threadIdx.x], lh[threadIdx.x]);
    __syncthreads();
    if (threadIdx.x < R_REL) lh[threadIdx.x] = 0;
    __syncthreads();
    for (int i = c0 + threadIdx.x; i < cend; i += 256) {
        int r = et[i];
        int p = lbase[r] + atomicAdd(&lh[r], 1);
        srcp[p] = srcA[i];
        normp[p] = norm[i];
        inv2[p] = atomicAdd(&cnt2[dstA[i]], 1);
    }
}

// ---------------- K2: all-register barrier-free edge GEMM ------------------
// Wave w: rows (w>>1)*32..+32 of the 64-edge tile, cols (w&1)*64..+64.
// B frags from L2-resident Wt, A frags gathered from node_bf, no LDS.
__global__ __launch_bounds__(256, 3) void k_conv_gemm(
    const int* __restrict__ tile_rel, const int* __restrict__ tile_start,
    const int* __restrict__ tile_len, const int* __restrict__ ntiles_p,
    const int* __restrict__ srcp, const float* __restrict__ normp,
    const unsigned short* __restrict__ node_bf,
    const unsigned short* __restrict__ Wt, const int* __restrict__ inv2,
    unsigned short* __restrict__ t_out) {
    int tid = blockIdx.x;
    if (tid >= *ntiles_p) return;
    int r = tile_rel[tid], start = tile_start[tid], len = tile_len[tid];
    int t = threadIdx.x, w = t >> 6, lane = t & 63;
    int wr = (w >> 1) * 32, wc = (w & 1) * 64;
    int lrow = lane & 15, quad = lane >> 4;
    const unsigned short* Wr = Wt + (size_t)r * 16384;

    float mynorm = 0.f; int myp2 = 0;
    if (lane < 32) {
        int row = wr + lane;
        if (row < len) {
            mynorm = normp[start + row];
            myp2   = inv2[start + row];
        }
    }
    const bf16x8 zed = {0, 0, 0, 0, 0, 0, 0, 0};
    bf16x8 ball[4][4];
#pragma unroll
    for (int ks = 0; ks < 4; ++ks) {
        int cb = ks * 4 + quad;
#pragma unroll
        for (int j = 0; j < 4; ++j) {
            int o = wc + j * 16 + lrow;
            ball[ks][j] = *reinterpret_cast<const bf16x8*>(Wr + o * 128 + cb * 8);
        }
    }
    bf16x8 afr[4][2];
#pragma unroll
    for (int i = 0; i < 2; ++i) {
        int arow = wr + i * 16 + lrow;
        bool valid = arow < len;
        const unsigned short* ap =
            node_bf + (size_t)(valid ? srcp[start + arow] : srcp[start]) * 128;
#pragma unroll
        for (int ks = 0; ks < 4; ++ks) {
            bf16x8 x = *reinterpret_cast<const bf16x8*>(ap + (ks * 4 + quad) * 8);
            afr[ks][i] = valid ? x : zed;
        }
    }

    f32x4 acc[2][4];
#pragma unroll
    for (int i = 0; i < 2; ++i)
#pragma unroll
        for (int j = 0; j < 4; ++j) acc[i][j] = (f32x4){0.f, 0.f, 0.f, 0.f};
#pragma unroll
    for (int ks = 0; ks < 4; ++ks)
#pragma unroll
        for (int i = 0; i < 2; ++i)
#pragma unroll
            for (int j = 0; j < 4; ++j)
                acc[i][j] = __builtin_amdgcn_mfma_f32_16x16x32_bf16(
                    afr[ks][i], ball[ks][j], acc[i][j], 0, 0, 0);

    // epilogue: meta via shfl, scale, pack bf16, NT store 8B/lane
#pragma unroll
    for (int i = 0; i < 2; ++i) {
#pragma unroll
        for (int reg = 0; reg < 4; ++reg) {
            int idx = i * 16 + quad * 4 + reg;     // row within wave's 32
            float nm = __shfl(mynorm, idx);
            int p2   = __shfl(myp2, idx);
            int m = wr + idx;
            if (m < len) {
                float2 lo2 = make_float2(acc[i][0][reg] * nm, acc[i][1][reg] * nm);
                float2 hi2 = make_float2(acc[i][2][reg] * nm, acc[i][3][reg] * nm);
                __hip_bfloat162 blo = __float22bfloat162_rn(lo2);
                __hip_bfloat162 bhi = __float22bfloat162_rn(hi2);
                u32x2 st;
                st.x = *reinterpret_cast<unsigned int*>(&blo);
                st.y = *reinterpret_cast<unsigned int*>(&bhi);
                __builtin_nontemporal_store(st,
                    reinterpret_cast<u32x2*>(t_out + (size_t)p2 * 128 + wc + lrow * 4));
            }
        }
    }
}

// ---------------- K2b: wave-per-dst CSR reduce + bias/relu/resid + stats ---
__global__ __launch_bounds__(256) void k_reduce_fused(
    const unsigned short* __restrict__ t, const int* __restrict__ seg,
    const float* __restrict__ resid, const float* __restrict__ h_bias,
    float* __restrict__ h, float* __restrict__ colsum, float* __restrict__ colsumsq) {
    __shared__ float cs1[128], cs2[128], sbias[128];
    if (threadIdx.x < 128) {
        cs1[threadIdx.x] = 0.f; cs2[threadIdx.x] = 0.f;
        sbias[threadIdx.x] = h_bias[unperm(threadIdx.x)];
    }
    __syncthreads();
    int w = threadIdx.x >> 6, lane = threadIdx.x & 63;
    int g = lane >> 4, c = lane & 15;
    for (int k = 0; k < 4; ++k) {
        int d = blockIdx.x * 16 + k * 4 + w;
        int a = seg[d], b = seg[d + 1];
        float s[8];
#pragma unroll
        for (int kk = 0; kk < 8; ++kk) s[kk] = 0.f;
        int q = a + g;
        for (; q + 4 < b; q += 8) {
            u32x4 v0 = __builtin_nontemporal_load(reinterpret_cast<const u32x4*>(t + (size_t)q * 128 + c * 8));
            u32x4 v1 = __builtin_nontemporal_load(reinterpret_cast<const u32x4*>(t + (size_t)(q + 4) * 128 + c * 8));
#pragma unroll
            for (int kk = 0; kk < 4; ++kk) {
                s[2 * kk]     += bf2f_lo(v0[kk]) + bf2f_lo(v1[kk]);
                s[2 * kk + 1] += bf2f_hi(v0[kk]) + bf2f_hi(v1[kk]);
            }
        }
        for (; q < b; q += 4) {
            u32x4 v = __builtin_nontemporal_load(reinterpret_cast<const u32x4*>(t + (size_t)q * 128 + c * 8));
#pragma unroll
            for (int kk = 0; kk < 4; ++kk) {
                s[2 * kk]     += bf2f_lo(v[kk]);
                s[2 * kk + 1] += bf2f_hi(v[kk]);
            }
        }
#pragma unroll
        for (int kk = 0; kk < 8; ++kk) {           // cross-row-group reduce
            s[kk] += __shfl_xor(s[kk], 16);
            s[kk] += __shfl_xor(s[kk], 32);
        }
        if (g == 0) {
            const float* rp = resid + (size_t)d * 128 + c * 8;
            float4 r0 = *reinterpret_cast<const float4*>(rp);
            float4 r1 = *reinterpret_cast<const float4*>(rp + 4);
            float rr[8] = {r0.x, r0.y, r0.z, r0.w, r1.x, r1.y, r1.z, r1.w};
            float v[8];
#pragma unroll
            for (int kk = 0; kk < 8; ++kk)
                v[kk] = fmaxf(s[kk] + sbias[c * 8 + kk], 0.f) + rr[kk];
            float* hp = h + (size_t)d * 128 + c * 8;
            *reinterpret_cast<float4*>(hp)     = make_float4(v[0], v[1], v[2], v[3]);
            *reinterpret_cast<float4*>(hp + 4) = make_float4(v[4], v[5], v[6], v[7]);
#pragma unroll
            for (int kk = 0; kk < 8; ++kk) {
                atomicAdd(&cs1[c * 8 + kk], v[kk]);
                atomicAdd(&cs2[c * 8 + kk], v[kk] * v[kk]);
            }
        }
    }
    __syncthreads();
    if (threadIdx.x < 128) {
        atomicAdd(&colsum[threadIdx.x], cs1[threadIdx.x]);
        atomicAdd(&colsumsq[threadIdx.x], cs2[threadIdx.x]);
    }
}

// ---------------- K3: residual GEMM + fused fp32->bf16 conversion ----------
__global__ __launch_bounds__(256, 2) void k_resid_gemm(
    const float* __restrict__ node_feats, unsigned short* __restrict__ node_bf,
    const unsigned short* __restrict__ Wrest, const float* __restrict__ b_res,
    float* __restrict__ resid) {
    __shared__ unsigned short Alds[128 * 128];
    __shared__ unsigned short Blds[128 * 128];
    int row0 = blockIdx.x * 128;
    int t = threadIdx.x;
    int nrows = min(128, N_NODES - row0);
#pragma unroll
    for (int it = 0; it < 8; ++it) {
        int j = t + 256 * it;
        int o = j >> 4, c = j & 15, cs = c ^ (o & 15);
        async16(Wrest + o * 128 + cs * 8, &Blds[o * 128 + c * 8]);
    }
#pragma unroll
    for (int it = 0; it < 8; ++it) {               // load fp32, cvt, stage + emit
        int j = t + 256 * it;
        int p = j >> 4, cg = j & 15;
        if (p < nrows) {
            const float* sp = node_feats + (size_t)(row0 + p) * 128 + cg * 8;
            float4 f0 = *reinterpret_cast<const float4*>(sp);
            float4 f1 = *reinterpret_cast<const float4*>(sp + 4);
            __hip_bfloat162 b0 = __float22bfloat162_rn(make_float2(f0.x, f0.y));
            __hip_bfloat162 b1 = __float22bfloat162_rn(make_float2(f0.z, f0.w));
            __hip_bfloat162 b2 = __float22bfloat162_rn(make_float2(f1.x, f1.y));
            __hip_bfloat162 b3 = __float22bfloat162_rn(make_float2(f1.z, f1.w));
            u32x4 pk;
            pk.x = *reinterpret_cast<unsigned int*>(&b0);
            pk.y = *reinterpret_cast<unsigned int*>(&b1);
            pk.z = *reinterpret_cast<unsigned int*>(&b2);
            pk.w = *reinterpret_cast<unsigned int*>(&b3);
            int cl = cg ^ (p & 15);
            *reinterpret_cast<u32x4*>(&Alds[p * 128 + cl * 8]) = pk;
            *reinterpret_cast<u32x4*>(node_bf + (size_t)(row0 + p) * 128 + cg * 8) = pk;
        }
    }
    __syncthreads();

    int w = t >> 6, lane = t & 63;
    int wr = (w >> 1) * 64, wc = (w & 1) * 64;
    int lrow = lane & 15, quad = lane >> 4;
    f32x4 acc[4][4];
#pragma unroll
    for (int i = 0; i < 4; ++i)
#pragma unroll
        for (int j = 0; j < 4; ++j) acc[i][j] = (f32x4){0.f, 0.f, 0.f, 0.f};
#pragma unroll
    for (int ks = 0; ks < 4; ++ks) {
        int cbase = ks * 4 + quad;
        bf16x8 af[4], bfr[4];
#pragma unroll
        for (int i = 0; i < 4; ++i) {
            int row = wr + i * 16 + lrow;
            int cs = cbase ^ (row & 15);
            af[i] = *reinterpret_cast<const bf16x8*>(&Alds[row * 128 + cs * 8]);
        }
#pragma unroll
        for (int j = 0; j < 4; ++j) {
            int row = wc + j * 16 + lrow;
            int cs = cbase ^ (row & 15);
            bfr[j] = *reinterpret_cast<const bf16x8*>(&Blds[row * 128 + cs * 8]);
        }
#pragma unroll
        for (int i = 0; i < 4; ++i)
#pragma unroll
            for (int j = 0; j < 4; ++j)
                acc[i][j] = __builtin_amdgcn_mfma_f32_16x16x32_bf16(af[i], bfr[j], acc[i][j], 0, 0, 0);
    }
    float br0 = b_res[wc + lrow];
    float br1 = b_res[wc + 16 + lrow];
    float br2 = b_res[wc + 32 + lrow];
    float br3 = b_res[wc + 48 + lrow];
#pragma unroll
    for (int i = 0; i < 4; ++i) {
        int m0 = wr + i * 16 + quad * 4;
#pragma unroll
        for (int reg = 0; reg < 4; ++reg) {
            int grow = row0 + m0 + reg;
            if (grow < N_NODES) {
                float4 v;
                v.x = fmaxf(acc[i][0][reg] + br0, 0.f);
                v.y = fmaxf(acc[i][1][reg] + br1, 0.f);
                v.z = fmaxf(acc[i][2][reg] + br2, 0.f);
                v.w = fmaxf(acc[i][3][reg] + br3, 0.f);
                *reinterpret_cast<float4*>(resid + (size_t)grow * 128 + wc + lrow * 4) = v;
            }
        }
    }
}

// ---------------- K5: BN apply + unpermute to natural cols -----------------
__global__ void k_bn(float* __restrict__ h, const float* __restrict__ colsum,
                     const float* __restrict__ colsumsq, const float* __restrict__ gamma,
                     const float* __restrict__ beta) {
    __shared__ float sc[128], sh[128], tile[8][128];
    int t = threadIdx.x;
    if (t < 128) {
        int n = unperm(t);
        float m = colsum[t] * (1.f / N_NODES);
        float var = colsumsq[t] * (1.f / N_NODES) - m * m;
        float s = gamma[n] * rsqrtf(var + 1e-5f);
        sc[t] = s;
        sh[t] = beta[n] - m * s;
    }
    __syncthreads();
    int r = t >> 5;
    int p0 = (t & 31) * 4;
    int n0 = (p0 & 64) + ((p0 >> 2) & 15);
    for (int row0 = blockIdx.x * 8; row0 < N_NODES; row0 += gridDim.x * 8) {
        int row = row0 + r;
        float4 v = make_float4(0.f, 0.f, 0.f, 0.f);
        if (row < N_NODES) v = *reinterpret_cast<float4*>(h + (size_t)row * 128 + p0);
        v.x = v.x * sc[p0] + sh[p0];
        v.y = v.y * sc[p0 + 1] + sh[p0 + 1];
        v.z = v.z * sc[p0 + 2] + sh[p0 + 2];
        v.w = v.w * sc[p0 + 3] + sh[p0 + 3];
        tile[r][n0]      = v.x;
        tile[r][n0 + 16] = v.y;
        tile[r][n0 + 32] = v.z;
        tile[r][n0 + 48] = v.w;
        __syncthreads();
        if (row < N_NODES)
            *reinterpret_cast<float4*>(h + (size_t)row * 128 + p0) =
                *reinterpret_cast<float4*>(&tile[r][p0]);
        __syncthreads();
    }
}

extern "C" void kernel_launch(void* const* d_in, const int* in_sizes, int n_in,
                              void* d_out, int out_size, void* d_ws, size_t ws_size,
                              hipStream_t stream) {
    (void)in_sizes; (void)n_in; (void)out_size; (void)ws_size;
    const float* node_feats = (const float*)d_in[0];
    const int* src    = (const int*)d_in[1];
    const int* dst    = (const int*)d_in[2];
    const int* etype  = (const int*)d_in[3];
    const float* norm = (const float*)d_in[4];
    const float* basis = (const float*)d_in[5];
    const float* comp  = (const float*)d_in[6];
    const float* h_bias = (const float*)d_in[7];
    const float* W_res  = (const float*)d_in[8];
    const float* b_res  = (const float*)d_in[9];
    const float* gamma  = (const float*)d_in[10];
    const float* beta   = (const float*)d_in[11];

    char* ws = (char*)d_ws;
    int* ghist      = (int*)(ws + 0);
    int* cnt        = (int*)(ws + 1024);
    int* ntiles_p   = (int*)(ws + 2048);
    float* colsum   = (float*)(ws + 2560);
    float* colsumsq = (float*)(ws + 3072);
    int* tile_rel   = (int*)(ws + 8192);       // 40960
    int* tile_start = (int*)(ws + 49152);      // 40960
    int* tile_len   = (int*)(ws + 90112);      // 40960 -> 131072
    unsigned short* Wt      = (unsigned short*)(ws + 131072);    // 2129920 -> 2260992
    unsigned short* Wrest   = (unsigned short*)(ws + 2260992);   // 32768   -> 2293760
    unsigned short* node_bf = (unsigned short*)(ws + 2293760);   // 5120000 -> 7413760
    int* srcp       = (int*)(ws + 7413760);    // 2560000 -> 9973760
    float* normp    = (float*)(ws + 9973760);  // 2560000 -> 12533760
    int* inv2       = (int*)(ws + 12533760);   // 2560000 -> 15093760
    float* resid    = (float*)(ws + 15093760); // 10240000 -> 25333760
    int* seg        = (int*)(ws + 25333760);   // 80004 -> 25413764, pad
    int* gh2        = (int*)(ws + 25413776);   // 80000 -> 25493776
    int* cnt2       = (int*)(ws + 25493776);   // 80000 -> 25573776
    int* bsum       = (int*)(ws + 25573776);   // 320   -> 25574096
    const long T_BASE = 25574096L;             // 16B aligned
    float* W32      = (float*)(ws + T_BASE);   // aliased: dead before conv
    unsigned short* t_buf = (unsigned short*)(ws + T_BASE);      // 163.84 MB
    float* hacc = (float*)d_out;

    hipMemsetAsync(ws, 0, 8192, stream);
    hipMemsetAsync(gh2, 0, N_NODES * 4, stream);

    k_basis_gemm<<<dim3(64, 5), 256, 0, stream>>>(comp, basis, W32);
    k_transpose_bf16<<<R_REL * 4, 256, 0, stream>>>(W32, Wt);
    k_transpose_bf16<<<4, 256, 0, stream>>>(W_res, Wrest);
    k_hist2<<<512, 256, 0, stream>>>(etype, dst, ghist, gh2);
    k_scanA<<<80, 256, 0, stream>>>(gh2, bsum);
    k_scan_small<<<1, 256, 0, stream>>>(ghist, bsum, cnt, ntiles_p,
                                        tile_rel, tile_start, tile_len);
    k_scanC<<<80, 256, 0, stream>>>(gh2, bsum, cnt2, seg);
    k_scatter2<<<(E_EDGES + SCAT_CH - 1) / SCAT_CH, 256, 0, stream>>>(
        etype, src, dst, norm, cnt, cnt2, srcp, normp, inv2);
    k_resid_gemm<<<(N_NODES + 127) / 128, 256, 0, stream>>>(
        node_feats, node_bf, Wrest, b_res, resid);
    k_conv_gemm<<<MAX_TILES, 256, 0, stream>>>(tile_rel, tile_start, tile_len, ntiles_p,
                                               srcp, normp, node_bf, Wt, inv2, t_buf);
    k_reduce_fused<<<N_NODES / 16, 256, 0, stream>>>(t_buf, seg, resid, h_bias,
                                                     hacc, colsum, colsumsq);
    k_bn<<<2500, 256, 0, stream>>>(hacc, colsum, colsumsq, gamma, beta);
}

// Round 8
// 376.601 us; speedup vs baseline: 1.0849x; 1.0849x over previous
//
#include <hip/hip_runtime.h>
#include <hip/hip_bf16.h>

// RGCN layer, MI355X — round 8.
// r7 post-mortem: all-register conv regressed (per-lane scattered 16B loads
// kill TA coalescing). r5's async16 staging pattern (4x256B segments/instr)
// was the win; its cost was the per-tile barrier draining fresh gathers.
// conv-v5: persistent blocks (768, 3/CU), contiguous tile ranges, W staged
// once per rel-run, A(next) prefetched into REGISTERS during current tile's
// MFMA -> barrier waits are pre-drained. Meta via lane regs + shfl.
// Also: reduce 4-deep MLP; transposes merged; zeroing fused into basis_gemm
// (13 -> 11 dispatches).

#define N_NODES 20000
#define E_EDGES 640000
#define R_REL   65
#define TM      64
#define MAX_TILES 10240
#define SCAT_CH 2560
#define NB_CONV 768

typedef __attribute__((ext_vector_type(8))) short bf16x8;
typedef __attribute__((ext_vector_type(4))) float f32x4;
typedef __attribute__((ext_vector_type(4))) unsigned int u32x4;
typedef __attribute__((ext_vector_type(2))) unsigned int u32x2;

__device__ __forceinline__ unsigned short f2bf(float x) {
    union { float f; unsigned int u; } c; c.f = x;
    unsigned int b = c.u + 0x7fffu + ((c.u >> 16) & 1u);   // RTNE
    return (unsigned short)(b >> 16);
}
__device__ __forceinline__ float bf2f_lo(unsigned int u) {
    union { unsigned int u; float f; } c; c.u = u << 16; return c.f;
}
__device__ __forceinline__ float bf2f_hi(unsigned int u) {
    union { unsigned int u; float f; } c; c.u = u & 0xffff0000u; return c.f;
}
__device__ __forceinline__ void async16(const void* g, void* l) {
    __builtin_amdgcn_global_load_lds(
        (const __attribute__((address_space(1))) unsigned int*)g,
        (__attribute__((address_space(3))) unsigned int*)l, 16, 0, 0);
}
__device__ __forceinline__ int unperm(int p) {      // permuted pos -> true col
    return (p & 64) + ((p & 3) << 4) + ((p >> 2) & 15);
}

// ---------------- K0a: basis GEMM + fused workspace zeroing ----------------
__global__ void k_basis_gemm(const float* __restrict__ comp,
                             const float* __restrict__ basis,
                             float* __restrict__ W32,
                             int* __restrict__ ctrl, int* __restrict__ gh2) {
    if (blockIdx.y == 0) {                    // fused zero: ctrl 8KB + gh2
        for (int i = blockIdx.x * 256 + threadIdx.x; i < 2048; i += 64 * 256)
            ctrl[i] = 0;
        for (int i = blockIdx.x * 256 + threadIdx.x; i < N_NODES; i += 64 * 256)
            gh2[i] = 0;
    }
    __shared__ float lc[16 * 65];
    int r0 = blockIdx.y * 16;
    int col = blockIdx.x * 256 + threadIdx.x;
    for (int j = threadIdx.x; j < 16 * 65; j += 256) {
        int rr = r0 + j / 65;
        lc[j] = (rr < R_REL) ? comp[rr * 65 + (j % 65)] : 0.f;
    }
    __syncthreads();
    float acc[16];
#pragma unroll
    for (int j = 0; j < 16; ++j) acc[j] = 0.f;
    for (int k = 0; k < 65; ++k) {
        float v = basis[k * 16384 + col];
#pragma unroll
        for (int j = 0; j < 16; ++j) acc[j] += lc[j * 65 + k] * v;
    }
#pragma unroll
    for (int j = 0; j < 16; ++j) {
        int rr = r0 + j;
        if (rr < R_REL) W32[rr * 16384 + col] = acc[j];
    }
}

// ---------------- K0b: both transposes in one launch -----------------------
__global__ void k_transpose_all(const float* __restrict__ W32,
                                unsigned short* __restrict__ Wt,
                                const float* __restrict__ Wresf,
                                unsigned short* __restrict__ Wrest) {
    __shared__ float tile[64][65];
    int b = blockIdx.x;
    const float* s; unsigned short* d; int sub;
    if (b < R_REL * 4) {
        s = W32 + (size_t)(b >> 2) * 16384;
        d = Wt + (size_t)(b >> 2) * 16384;
        sub = b & 3;
    } else {
        s = Wresf; d = Wrest; sub = b - R_REL * 4;
    }
    int ot = (sub >> 1) & 1, itl = sub & 1;
    int tx = threadIdx.x & 63, ty = threadIdx.x >> 6;
    for (int it = 0; it < 16; ++it) {
        int i = ty + it * 4;
        tile[i][tx] = s[(itl * 64 + i) * 128 + ot * 64 + tx];
    }
    __syncthreads();
    for (int it = 0; it < 16; ++it) {
        int o = ty + it * 4;
        d[(ot * 64 + o) * 128 + itl * 64 + tx] = f2bf(tile[tx][o]);
    }
}

// ---------------- K1a: etype histogram + dst histogram, one pass -----------
__global__ void k_hist2(const int* __restrict__ et, const int* __restrict__ dstA,
                        int* __restrict__ ghist, int* __restrict__ gh2) {
    __shared__ int lh[R_REL];
    if (threadIdx.x < R_REL) lh[threadIdx.x] = 0;
    __syncthreads();
    for (int i = blockIdx.x * 256 + threadIdx.x; i < E_EDGES; i += gridDim.x * 256) {
        atomicAdd(&lh[et[i]], 1);
        atomicAdd(&gh2[dstA[i]], 1);
    }
    __syncthreads();
    if (threadIdx.x < R_REL) atomicAdd(&ghist[threadIdx.x], lh[threadIdx.x]);
}

// ---------------- K1b: per-block partial sums of gh2 -----------------------
__global__ void k_scanA(const int* __restrict__ gh2, int* __restrict__ bsum) {
    int i = blockIdx.x * 256 + threadIdx.x;
    int v = (i < N_NODES) ? gh2[i] : 0;
    __shared__ int red[256];
    red[threadIdx.x] = v;
    __syncthreads();
    for (int off = 128; off > 0; off >>= 1) {
        if (threadIdx.x < off) red[threadIdx.x] += red[threadIdx.x + off];
        __syncthreads();
    }
    if (threadIdx.x == 0) bsum[blockIdx.x] = red[0];
}

// ---------------- K1c: small scans: bsum[80], ghist->base, tile descs ------
__global__ void k_scan_small(const int* __restrict__ ghist, int* __restrict__ bsum,
                             int* __restrict__ cnt, int* __restrict__ ntiles_p,
                             int* __restrict__ tile_rel, int* __restrict__ tile_start,
                             int* __restrict__ tile_len) {
    __shared__ int base[R_REL + 1], tbase[R_REL + 1];
    int t = threadIdx.x, w = t >> 6, lane = t & 63;
    if (w == 0) {                                   // exclusive scan bsum[80]
        int v0 = bsum[lane];
        int x = v0;
#pragma unroll
        for (int off = 1; off < 64; off <<= 1) {
            int y = __shfl_up(x, off);
            if (lane >= off) x += y;
        }
        int tot0 = __shfl(x, 63);
        int v1 = (lane < 16) ? bsum[64 + lane] : 0;
        int x1 = v1;
#pragma unroll
        for (int off = 1; off < 16; off <<= 1) {
            int y = __shfl_up(x1, off);
            if (lane >= off) x1 += y;
        }
        bsum[lane] = x - v0;
        if (lane < 16) bsum[64 + lane] = (x1 - v1) + tot0;
    } else if (w == 1) {                            // exclusive scan ghist[65]
        int v = (lane < 64) ? ghist[lane] : 0;
        int x = v;
#pragma unroll
        for (int off = 1; off < 64; off <<= 1) {
            int y = __shfl_up(x, off);
            if (lane >= off) x += y;
        }
        base[lane] = x - v;
        if (lane == 63) {
            base[64] = x;
            base[65] = x + ghist[64];
        }
    }
    __syncthreads();
    if (t == 0) {
        int tb = 0;
        for (int r = 0; r < R_REL; ++r) {
            tbase[r] = tb;
            int h = base[r + 1] - base[r];
            tb += (h + TM - 1) / TM;
        }
        *ntiles_p = tb;
    }
    __syncthreads();
    if (t < R_REL) {
        cnt[t] = base[t];
        int s = base[t], e = base[t + 1], j = tbase[t];
        while (s < e) {
            int len = min(TM, e - s);
            tile_rel[j] = t; tile_start[j] = s; tile_len[j] = len;
            ++j; s += len;
        }
    }
}

// ---------------- K1d: block scan -> cnt2 (dst bases) + seg ----------------
__global__ void k_scanC(const int* __restrict__ gh2, const int* __restrict__ bsum,
                        int* __restrict__ cnt2, int* __restrict__ seg) {
    int i = blockIdx.x * 256 + threadIdx.x;
    int v = (i < N_NODES) ? gh2[i] : 0;
    __shared__ int red[256];
    red[threadIdx.x] = v;
    __syncthreads();
    for (int off = 1; off < 256; off <<= 1) {
        int x = (threadIdx.x >= off) ? red[threadIdx.x - off] : 0;
        __syncthreads();
        red[threadIdx.x] += x;
        __syncthreads();
    }
    int excl = red[threadIdx.x] - v + bsum[blockIdx.x];
    if (i < N_NODES) {
        cnt2[i] = excl;
        seg[i] = excl;
        if (i == N_NODES - 1) seg[N_NODES] = excl + v;   // == E
    }
}

// ---------------- K1e: rel scatter + dst-position assignment ---------------
__global__ void k_scatter2(const int* __restrict__ et, const int* __restrict__ srcA,
                           const int* __restrict__ dstA, const float* __restrict__ norm,
                           int* __restrict__ cnt, int* __restrict__ cnt2,
                           int* __restrict__ srcp, float* __restrict__ normp,
                           int* __restrict__ inv2) {
    __shared__ int lh[R_REL], lbase[R_REL];
    int c0 = blockIdx.x * SCAT_CH;
    int cend = min(c0 + SCAT_CH, E_EDGES);
    if (threadIdx.x < R_REL) lh[threadIdx.x] = 0;
    __syncthreads();
    for (int i = c0 + threadIdx.x; i < cend; i += 256) atomicAdd(&lh[et[i]], 1);
    __syncthreads();
    if (threadIdx.x < R_REL && lh[threadIdx.x] > 0)
        lbase[threadIdx.x] = atomicAdd(&cnt[threadIdx.x], lh[threadIdx.x]);
    __syncthreads();
    if (threadIdx.x < R_REL) lh[threadIdx.x] = 0;
    __syncthreads();
    for (int i = c0 + threadIdx.x; i < cend; i += 256) {
        int r = et[i];
        int p = lbase[r] + atomicAdd(&lh[r], 1);
        srcp[p] = srcA[i];
        normp[p] = norm[i];
        inv2[p] = atomicAdd(&cnt2[dstA[i]], 1);
    }
}

// ---------------- K2: persistent-block pipelined edge GEMM -----------------
// 768 blocks, contiguous tile ranges. W staged once per rel-run (async16);
// A(next) prefetched to registers during MFMA(cur); LDS 48KB -> 3 blocks/CU.
__global__ __launch_bounds__(256, 3) void k_conv_gemm(
    const int* __restrict__ tile_rel, const int* __restrict__ tile_start,
    const int* __restrict__ tile_len, const int* __restrict__ ntiles_p,
    const int* __restrict__ srcp, const float* __restrict__ normp,
    const unsigned short* __restrict__ node_bf,
    const unsigned short* __restrict__ Wt, const int* __restrict__ inv2,
    unsigned short* __restrict__ t_out) {
    __shared__ unsigned short Blds[128 * 128];
    __shared__ unsigned short Alds[64 * 128];
    int nt = *ntiles_p;
    int tpb = (nt + NB_CONV - 1) / NB_CONV;
    int s0 = blockIdx.x * tpb, s1 = min(nt, s0 + tpb);
    if (s0 >= s1) return;
    int t = threadIdx.x, w = t >> 6, lane = t & 63;
    int wr = (w >> 1) * 32, wc = (w & 1) * 64;
    int lrow = lane & 15, quad = lane >> 4;
    int pr = t >> 4, cc = t & 15;
    unsigned short* ldsA = &Alds[pr * 128 + cc * 8];
    int curRel = -1;

    u32x4 apf[4];
    {
        int start = tile_start[s0], len = tile_len[s0];
#pragma unroll
        for (int it = 0; it < 4; ++it) {
            int p = pr + 16 * it;
            u32x4 v = {0u, 0u, 0u, 0u};
            if (p < len) {
                int cs = cc ^ (p & 15);
                v = *reinterpret_cast<const u32x4*>(
                    node_bf + (size_t)srcp[start + p] * 128 + cs * 8);
            }
            apf[it] = v;
        }
    }

    for (int s = s0; s < s1; ++s) {
        int r = tile_rel[s], start = tile_start[s], len = tile_len[s];
        bool newrel = (r != curRel);
        __syncthreads();                       // #1: Alds free, stores drained
        if (newrel) {
            const unsigned short* Wr = Wt + (size_t)r * 16384;
#pragma unroll
            for (int it = 0; it < 8; ++it) {
                int j = t + 256 * it;
                int o = j >> 4, c = j & 15, cs = c ^ (o & 15);
                async16(Wr + o * 128 + cs * 8, &Blds[o * 128 + c * 8]);
            }
            curRel = r;
        }
#pragma unroll
        for (int it = 0; it < 4; ++it)
            *reinterpret_cast<u32x4*>(ldsA + it * 16 * 128) = apf[it];
        __syncthreads();                       // #2: Alds (+W) visible

        if (s + 1 < s1) {                      // prefetch next A -> regs
            int nstart = tile_start[s + 1], nlen = tile_len[s + 1];
#pragma unroll
            for (int it = 0; it < 4; ++it) {
                int p = pr + 16 * it;
                u32x4 v = {0u, 0u, 0u, 0u};
                if (p < nlen) {
                    int cs = cc ^ (p & 15);
                    v = *reinterpret_cast<const u32x4*>(
                        node_bf + (size_t)srcp[nstart + p] * 128 + cs * 8);
                }
                apf[it] = v;
            }
        }
        float mynorm = 0.f; int myp2 = 0;
        if (lane < 32) {
            int row = wr + lane;
            if (row < len) {
                mynorm = normp[start + row];
                myp2   = inv2[start + row];
            }
        }

        f32x4 acc[2][4];
#pragma unroll
        for (int i = 0; i < 2; ++i)
#pragma unroll
            for (int j = 0; j < 4; ++j) acc[i][j] = (f32x4){0.f, 0.f, 0.f, 0.f};
#pragma unroll
        for (int ks = 0; ks < 4; ++ks) {
            int cbase = ks * 4 + quad;
            int cs = cbase ^ lrow;             // row&15 == lrow for A and B
            bf16x8 af[2], bfr[4];
#pragma unroll
            for (int i = 0; i < 2; ++i) {
                int row = wr + i * 16 + lrow;
                af[i] = *reinterpret_cast<const bf16x8*>(&Alds[row * 128 + cs * 8]);
            }
#pragma unroll
            for (int j = 0; j < 4; ++j) {
                int row = wc + j * 16 + lrow;
                bfr[j] = *reinterpret_cast<const bf16x8*>(&Blds[row * 128 + cs * 8]);
            }
#pragma unroll
            for (int i = 0; i < 2; ++i)
#pragma unroll
                for (int j = 0; j < 4; ++j)
                    acc[i][j] = __builtin_amdgcn_mfma_f32_16x16x32_bf16(
                        af[i], bfr[j], acc[i][j], 0, 0, 0);
        }

        // epilogue: meta via shfl, scale, pack bf16, NT store 8B/lane
#pragma unroll
        for (int i = 0; i < 2; ++i) {
#pragma unroll
            for (int reg = 0; reg < 4; ++reg) {
                int idx = i * 16 + quad * 4 + reg;
                float nm = __shfl(mynorm, idx);
                int p2   = __shfl(myp2, idx);
                int m = wr + idx;
                if (m < len) {
                    float2 lo2 = make_float2(acc[i][0][reg] * nm, acc[i][1][reg] * nm);
                    float2 hi2 = make_float2(acc[i][2][reg] * nm, acc[i][3][reg] * nm);
                    __hip_bfloat162 blo = __float22bfloat162_rn(lo2);
                    __hip_bfloat162 bhi = __float22bfloat162_rn(hi2);
                    u32x2 st;
                    st.x = *reinterpret_cast<unsigned int*>(&blo);
                    st.y = *reinterpret_cast<unsigned int*>(&bhi);
                    __builtin_nontemporal_store(st,
                        reinterpret_cast<u32x2*>(t_out + (size_t)p2 * 128 + wc + lrow * 4));
                }
            }
        }
    }
}

// ---------------- K2b: wave-per-dst CSR reduce, 4-deep MLP -----------------
__global__ __launch_bounds__(256) void k_reduce_fused(
    const unsigned short* __restrict__ t, const int* __restrict__ seg,
    const float* __restrict__ resid, const float* __restrict__ h_bias,
    float* __restrict__ h, float* __restrict__ colsum, float* __restrict__ colsumsq) {
    __shared__ float cs1[128], cs2[128], sbias[128];
    if (threadIdx.x < 128) {
        cs1[threadIdx.x] = 0.f; cs2[threadIdx.x] = 0.f;
        sbias[threadIdx.x] = h_bias[unperm(threadIdx.x)];
    }
    __syncthreads();
    int w = threadIdx.x >> 6, lane = threadIdx.x & 63;
    int g = lane >> 4, c = lane & 15;
    for (int k = 0; k < 4; ++k) {
        int d = blockIdx.x * 16 + k * 4 + w;
        int a = seg[d], b = seg[d + 1];
        float s[8];
#pragma unroll
        for (int kk = 0; kk < 8; ++kk) s[kk] = 0.f;
        int q = a + g;
        for (; q + 12 < b; q += 16) {
            u32x4 v0 = __builtin_nontemporal_load(reinterpret_cast<const u32x4*>(t + (size_t)q * 128 + c * 8));
            u32x4 v1 = __builtin_nontemporal_load(reinterpret_cast<const u32x4*>(t + (size_t)(q + 4) * 128 + c * 8));
            u32x4 v2 = __builtin_nontemporal_load(reinterpret_cast<const u32x4*>(t + (size_t)(q + 8) * 128 + c * 8));
            u32x4 v3 = __builtin_nontemporal_load(reinterpret_cast<const u32x4*>(t + (size_t)(q + 12) * 128 + c * 8));
#pragma unroll
            for (int kk = 0; kk < 4; ++kk) {
                s[2 * kk]     += bf2f_lo(v0[kk]) + bf2f_lo(v1[kk]) + bf2f_lo(v2[kk]) + bf2f_lo(v3[kk]);
                s[2 * kk + 1] += bf2f_hi(v0[kk]) + bf2f_hi(v1[kk]) + bf2f_hi(v2[kk]) + bf2f_hi(v3[kk]);
            }
        }
        for (; q < b; q += 4) {
            u32x4 v = __builtin_nontemporal_load(reinterpret_cast<const u32x4*>(t + (size_t)q * 128 + c * 8));
#pragma unroll
            for (int kk = 0; kk < 4; ++kk) {
                s[2 * kk]     += bf2f_lo(v[kk]);
                s[2 * kk + 1] += bf2f_hi(v[kk]);
            }
        }
#pragma unroll
        for (int kk = 0; kk < 8; ++kk) {
            s[kk] += __shfl_xor(s[kk], 16);
            s[kk] += __shfl_xor(s[kk], 32);
        }
        if (g == 0) {
            const float* rp = resid + (size_t)d * 128 + c * 8;
            float4 r0 = *reinterpret_cast<const float4*>(rp);
            float4 r1 = *reinterpret_cast<const float4*>(rp + 4);
            float rr[8] = {r0.x, r0.y, r0.z, r0.w, r1.x, r1.y, r1.z, r1.w};
            float v[8];
#pragma unroll
            for (int kk = 0; kk < 8; ++kk)
                v[kk] = fmaxf(s[kk] + sbias[c * 8 + kk], 0.f) + rr[kk];
            float* hp = h + (size_t)d * 128 + c * 8;
            *reinterpret_cast<float4*>(hp)     = make_float4(v[0], v[1], v[2], v[3]);
            *reinterpret_cast<float4*>(hp + 4) = make_float4(v[4], v[5], v[6], v[7]);
#pragma unroll
            for (int kk = 0; kk < 8; ++kk) {
                atomicAdd(&cs1[c * 8 + kk], v[kk]);
                atomicAdd(&cs2[c * 8 + kk], v[kk] * v[kk]);
            }
        }
    }
    __syncthreads();
    if (threadIdx.x < 128) {
        atomicAdd(&colsum[threadIdx.x], cs1[threadIdx.x]);
        atomicAdd(&colsumsq[threadIdx.x], cs2[threadIdx.x]);
    }
}

// ---------------- K3: residual GEMM + fused fp32->bf16 conversion ----------
__global__ __launch_bounds__(256, 2) void k_resid_gemm(
    const float* __restrict__ node_feats, unsigned short* __restrict__ node_bf,
    const unsigned short* __restrict__ Wrest, const float* __restrict__ b_res,
    float* __restrict__ resid) {
    __shared__ unsigned short Alds[128 * 128];
    __shared__ unsigned short Blds[128 * 128];
    int row0 = blockIdx.x * 128;
    int t = threadIdx.x;
    int nrows = min(128, N_NODES - row0);
#pragma unroll
    for (int it = 0; it < 8; ++it) {
        int j = t + 256 * it;
        int o = j >> 4, c = j & 15, cs = c ^ (o & 15);
        async16(Wrest + o * 128 + cs * 8, &Blds[o * 128 + c * 8]);
    }
#pragma unroll
    for (int it = 0; it < 8; ++it) {               // load fp32, cvt, stage + emit
        int j = t + 256 * it;
        int p = j >> 4, cg = j & 15;
        if (p < nrows) {
            const float* sp = node_feats + (size_t)(row0 + p) * 128 + cg * 8;
            float4 f0 = *reinterpret_cast<const float4*>(sp);
            float4 f1 = *reinterpret_cast<const float4*>(sp + 4);
            __hip_bfloat162 b0 = __float22bfloat162_rn(make_float2(f0.x, f0.y));
            __hip_bfloat162 b1 = __float22bfloat162_rn(make_float2(f0.z, f0.w));
            __hip_bfloat162 b2 = __float22bfloat162_rn(make_float2(f1.x, f1.y));
            __hip_bfloat162 b3 = __float22bfloat162_rn(make_float2(f1.z, f1.w));
            u32x4 pk;
            pk.x = *reinterpret_cast<unsigned int*>(&b0);
            pk.y = *reinterpret_cast<unsigned int*>(&b1);
            pk.z = *reinterpret_cast<unsigned int*>(&b2);
            pk.w = *reinterpret_cast<unsigned int*>(&b3);
            int cl = cg ^ (p & 15);
            *reinterpret_cast<u32x4*>(&Alds[p * 128 + cl * 8]) = pk;
            *reinterpret_cast<u32x4*>(node_bf + (size_t)(row0 + p) * 128 + cg * 8) = pk;
        }
    }
    __syncthreads();

    int w = t >> 6, lane = t & 63;
    int wr = (w >> 1) * 64, wc = (w & 1) * 64;
    int lrow = lane & 15, quad = lane >> 4;
    f32x4 acc[4][4];
#pragma unroll
    for (int i = 0; i < 4; ++i)
#pragma unroll
        for (int j = 0; j < 4; ++j) acc[i][j] = (f32x4){0.f, 0.f, 0.f, 0.f};
#pragma unroll
    for (int ks = 0; ks < 4; ++ks) {
        int cbase = ks * 4 + quad;
        int cs = cbase ^ lrow;
        bf16x8 af[4], bfr[4];
#pragma unroll
        for (int i = 0; i < 4; ++i) {
            int row = wr + i * 16 + lrow;
            af[i] = *reinterpret_cast<const bf16x8*>(&Alds[row * 128 + cs * 8]);
        }
#pragma unroll
        for (int j = 0; j < 4; ++j) {
            int row = wc + j * 16 + lrow;
            bfr[j] = *reinterpret_cast<const bf16x8*>(&Blds[row * 128 + cs * 8]);
        }
#pragma unroll
        for (int i = 0; i < 4; ++i)
#pragma unroll
            for (int j = 0; j < 4; ++j)
                acc[i][j] = __builtin_amdgcn_mfma_f32_16x16x32_bf16(af[i], bfr[j], acc[i][j], 0, 0, 0);
    }
    float br0 = b_res[wc + lrow];
    float br1 = b_res[wc + 16 + lrow];
    float br2 = b_res[wc + 32 + lrow];
    float br3 = b_res[wc + 48 + lrow];
#pragma unroll
    for (int i = 0; i < 4; ++i) {
        int m0 = wr + i * 16 + quad * 4;
#pragma unroll
        for (int reg = 0; reg < 4; ++reg) {
            int grow = row0 + m0 + reg;
            if (grow < N_NODES) {
                float4 v;
                v.x = fmaxf(acc[i][0][reg] + br0, 0.f);
                v.y = fmaxf(acc[i][1][reg] + br1, 0.f);
                v.z = fmaxf(acc[i][2][reg] + br2, 0.f);
                v.w = fmaxf(acc[i][3][reg] + br3, 0.f);
                *reinterpret_cast<float4*>(resid + (size_t)grow * 128 + wc + lrow * 4) = v;
            }
        }
    }
}

// ---------------- K5: BN apply + unpermute to natural cols -----------------
__global__ void k_bn(float* __restrict__ h, const float* __restrict__ colsum,
                     const float* __restrict__ colsumsq, const float* __restrict__ gamma,
                     const float* __restrict__ beta) {
    __shared__ float sc[128], sh[128], tile[8][128];
    int t = threadIdx.x;
    if (t < 128) {
        int n = unperm(t);
        float m = colsum[t] * (1.f / N_NODES);
        float var = colsumsq[t] * (1.f / N_NODES) - m * m;
        float s = gamma[n] * rsqrtf(var + 1e-5f);
        sc[t] = s;
        sh[t] = beta[n] - m * s;
    }
    __syncthreads();
    int r = t >> 5;
    int p0 = (t & 31) * 4;
    int n0 = (p0 & 64) + ((p0 >> 2) & 15);
    for (int row0 = blockIdx.x * 8; row0 < N_NODES; row0 += gridDim.x * 8) {
        int row = row0 + r;
        float4 v = make_float4(0.f, 0.f, 0.f, 0.f);
        if (row < N_NODES) v = *reinterpret_cast<float4*>(h + (size_t)row * 128 + p0);
        v.x = v.x * sc[p0] + sh[p0];
        v.y = v.y * sc[p0 + 1] + sh[p0 + 1];
        v.z = v.z * sc[p0 + 2] + sh[p0 + 2];
        v.w = v.w * sc[p0 + 3] + sh[p0 + 3];
        tile[r][n0]      = v.x;
        tile[r][n0 + 16] = v.y;
        tile[r][n0 + 32] = v.z;
        tile[r][n0 + 48] = v.w;
        __syncthreads();
        if (row < N_NODES)
            *reinterpret_cast<float4*>(h + (size_t)row * 128 + p0) =
                *reinterpret_cast<float4*>(&tile[r][p0]);
        __syncthreads();
    }
}

extern "C" void kernel_launch(void* const* d_in, const int* in_sizes, int n_in,
                              void* d_out, int out_size, void* d_ws, size_t ws_size,
                              hipStream_t stream) {
    (void)in_sizes; (void)n_in; (void)out_size; (void)ws_size;
    const float* node_feats = (const float*)d_in[0];
    const int* src    = (const int*)d_in[1];
    const int* dst    = (const int*)d_in[2];
    const int* etype  = (const int*)d_in[3];
    const float* norm = (const float*)d_in[4];
    const float* basis = (const float*)d_in[5];
    const float* comp  = (const float*)d_in[6];
    const float* h_bias = (const float*)d_in[7];
    const float* W_res  = (const float*)d_in[8];
    const float* b_res  = (const float*)d_in[9];
    const float* gamma  = (const float*)d_in[10];
    const float* beta   = (const float*)d_in[11];

    char* ws = (char*)d_ws;
    int* ctrl       = (int*)(ws + 0);          // first 8KB zeroed in basis_gemm
    int* ghist      = (int*)(ws + 0);
    int* cnt        = (int*)(ws + 1024);
    int* ntiles_p   = (int*)(ws + 2048);
    float* colsum   = (float*)(ws + 2560);
    float* colsumsq = (float*)(ws + 3072);
    int* tile_rel   = (int*)(ws + 8192);       // 40960
    int* tile_start = (int*)(ws + 49152);      // 40960
    int* tile_len   = (int*)(ws + 90112);      // 40960 -> 131072
    unsigned short* Wt      = (unsigned short*)(ws + 131072);    // 2129920 -> 2260992
    unsigned short* Wrest   = (unsigned short*)(ws + 2260992);   // 32768   -> 2293760
    unsigned short* node_bf = (unsigned short*)(ws + 2293760);   // 5120000 -> 7413760
    int* srcp       = (int*)(ws + 7413760);    // 2560000 -> 9973760
    float* normp    = (float*)(ws + 9973760);  // 2560000 -> 12533760
    int* inv2       = (int*)(ws + 12533760);   // 2560000 -> 15093760
    float* resid    = (float*)(ws + 15093760); // 10240000 -> 25333760
    int* seg        = (int*)(ws + 25333760);   // 80004 -> 25413764, pad
    int* gh2        = (int*)(ws + 25413776);   // 80000 -> 25493776
    int* cnt2       = (int*)(ws + 25493776);   // 80000 -> 25573776
    int* bsum       = (int*)(ws + 25573776);   // 320   -> 25574096
    const long T_BASE = 25574096L;             // 16B aligned
    float* W32      = (float*)(ws + T_BASE);   // aliased: dead before conv
    unsigned short* t_buf = (unsigned short*)(ws + T_BASE);      // 163.84 MB
    float* hacc = (float*)d_out;

    k_basis_gemm<<<dim3(64, 5), 256, 0, stream>>>(comp, basis, W32, ctrl, gh2);
    k_transpose_all<<<R_REL * 4 + 4, 256, 0, stream>>>(W32, Wt, W_res, Wrest);
    k_hist2<<<512, 256, 0, stream>>>(etype, dst, ghist, gh2);
    k_scanA<<<80, 256, 0, stream>>>(gh2, bsum);
    k_scan_small<<<1, 256, 0, stream>>>(ghist, bsum, cnt, ntiles_p,
                                        tile_rel, tile_start, tile_len);
    k_scanC<<<80, 256, 0, stream>>>(gh2, bsum, cnt2, seg);
    k_scatter2<<<(E_EDGES + SCAT_CH - 1) / SCAT_CH, 256, 0, stream>>>(
        etype, src, dst, norm, cnt, cnt2, srcp, normp, inv2);
    k_resid_gemm<<<(N_NODES + 127) / 128, 256, 0, stream>>>(
        node_feats, node_bf, Wrest, b_res, resid);
    k_conv_gemm<<<NB_CONV, 256, 0, stream>>>(tile_rel, tile_start, tile_len, ntiles_p,
                                             srcp, normp, node_bf, Wt, inv2, t_buf);
    k_reduce_fused<<<N_NODES / 16, 256, 0, stream>>>(t_buf, seg, resid, h_bias,
                                                     hacc, colsum, colsumsq);
    k_bn<<<2500, 256, 0, stream>>>(hacc, colsum, colsumsq, gamma, beta);
}

// Round 9
// 352.901 us; speedup vs baseline: 1.1578x; 1.0672x over previous
//
#include <hip/hip_runtime.h>
#include <hip/hip_bf16.h>

// RGCN layer, MI355X — round 9.
// r8 post-mortem: persistent conv + reg-prefetch = r7 pathology again
// (scattered per-lane loads); conv reverts to r5's proven 82us structure
// (per-tile blocks, async16 staging, 1 barrier, NT stores).
// Tail attack: 11 -> 8 graph nodes.
//   memset(88KB) -> k_prep1(basis||hists||cvt) -> k_prep2(transposes||scanA)
//   -> k_prep3(scanC w/ inline bsum prefix || tiles) -> k_scatter2
//   -> k_conv(resid tiles first + edge tiles) -> k_reduce_fused -> k_bn

#define N_NODES 20000
#define E_EDGES 640000
#define R_REL   65
#define TM      64
#define NB_RESID 313
#define MAX_TILES 10240
#define SCAT_CH 2560

typedef __attribute__((ext_vector_type(8))) short bf16x8;
typedef __attribute__((ext_vector_type(4))) float f32x4;
typedef __attribute__((ext_vector_type(4))) unsigned int u32x4;
typedef __attribute__((ext_vector_type(2))) unsigned int u32x2;

__device__ __forceinline__ unsigned short f2bf(float x) {
    union { float f; unsigned int u; } c; c.f = x;
    unsigned int b = c.u + 0x7fffu + ((c.u >> 16) & 1u);   // RTNE
    return (unsigned short)(b >> 16);
}
__device__ __forceinline__ float bf2f_lo(unsigned int u) {
    union { unsigned int u; float f; } c; c.u = u << 16; return c.f;
}
__device__ __forceinline__ float bf2f_hi(unsigned int u) {
    union { unsigned int u; float f; } c; c.u = u & 0xffff0000u; return c.f;
}
__device__ __forceinline__ void async16(const void* g, void* l) {
    __builtin_amdgcn_global_load_lds(
        (const __attribute__((address_space(1))) unsigned int*)g,
        (__attribute__((address_space(3))) unsigned int*)l, 16, 0, 0);
}
__device__ __forceinline__ int unperm(int p) {      // permuted pos -> true col
    return (p & 64) + ((p & 3) << 4) + ((p >> 2) & 15);
}

// ---------------- K1: basis GEMM || etype+dst hist || f32->bf16 cvt --------
__global__ void k_prep1(const float* __restrict__ comp, const float* __restrict__ basis,
                        float* __restrict__ W32, const int* __restrict__ et,
                        const int* __restrict__ dstA, int* __restrict__ ghist,
                        int* __restrict__ gh2, const float* __restrict__ node_feats,
                        unsigned short* __restrict__ node_bf) {
    __shared__ float lc[16 * 65];
    __shared__ int lh[R_REL];
    int b = blockIdx.x, t = threadIdx.x;
    if (b < 320) {                                  // basis GEMM
        int r0 = (b >> 6) * 16;
        int col = (b & 63) * 256 + t;
        for (int j = t; j < 16 * 65; j += 256) {
            int rr = r0 + j / 65;
            lc[j] = (rr < R_REL) ? comp[rr * 65 + (j % 65)] : 0.f;
        }
        __syncthreads();
        float acc[16];
#pragma unroll
        for (int j = 0; j < 16; ++j) acc[j] = 0.f;
        for (int k = 0; k < 65; ++k) {
            float v = basis[k * 16384 + col];
#pragma unroll
            for (int j = 0; j < 16; ++j) acc[j] += lc[j * 65 + k] * v;
        }
#pragma unroll
        for (int j = 0; j < 16; ++j) {
            int rr = r0 + j;
            if (rr < R_REL) W32[rr * 16384 + col] = acc[j];
        }
    } else if (b < 832) {                           // histograms
        if (t < R_REL) lh[t] = 0;
        __syncthreads();
        for (int i = (b - 320) * 256 + t; i < E_EDGES; i += 512 * 256) {
            atomicAdd(&lh[et[i]], 1);
            atomicAdd(&gh2[dstA[i]], 1);
        }
        __syncthreads();
        if (t < R_REL) atomicAdd(&ghist[t], lh[t]);
    } else {                                        // cvt fp32 -> bf16 (x4)
        int i = (b - 832) * 256 + t;
        if (i < N_NODES * 32) {
            float4 v = reinterpret_cast<const float4*>(node_feats)[i];
            __hip_bfloat162 b0 = __float22bfloat162_rn(make_float2(v.x, v.y));
            __hip_bfloat162 b1 = __float22bfloat162_rn(make_float2(v.z, v.w));
            u32x2 pk;
            pk.x = *reinterpret_cast<unsigned int*>(&b0);
            pk.y = *reinterpret_cast<unsigned int*>(&b1);
            reinterpret_cast<u32x2*>(node_bf)[i] = pk;
        }
    }
}

// ---------------- K2: transposes || scanA ----------------------------------
__global__ void k_prep2(const float* __restrict__ W32, unsigned short* __restrict__ Wt,
                        const float* __restrict__ Wresf, unsigned short* __restrict__ Wrest,
                        const int* __restrict__ gh2, int* __restrict__ bsum) {
    int b = blockIdx.x, t = threadIdx.x;
    if (b < 264) {                                  // transpose [i][o]->[o][i] bf16
        __shared__ float tile[64][65];
        const float* s; unsigned short* d; int sub;
        if (b < R_REL * 4) { s = W32 + (size_t)(b >> 2) * 16384; d = Wt + (size_t)(b >> 2) * 16384; sub = b & 3; }
        else { s = Wresf; d = Wrest; sub = b - R_REL * 4; }
        int ot = (sub >> 1) & 1, itl = sub & 1;
        int tx = t & 63, ty = t >> 6;
        for (int it = 0; it < 16; ++it) {
            int i = ty + it * 4;
            tile[i][tx] = s[(itl * 64 + i) * 128 + ot * 64 + tx];
        }
        __syncthreads();
        for (int it = 0; it < 16; ++it) {
            int o = ty + it * 4;
            d[(ot * 64 + o) * 128 + itl * 64 + tx] = f2bf(tile[tx][o]);
        }
    } else {                                        // scanA: per-block sums of gh2
        __shared__ int red[256];
        int i = (b - 264) * 256 + t;
        red[t] = (i < N_NODES) ? gh2[i] : 0;
        __syncthreads();
        for (int off = 128; off > 0; off >>= 1) {
            if (t < off) red[t] += red[t + off];
            __syncthreads();
        }
        if (t == 0) bsum[b - 264] = red[0];
    }
}

// ---------------- K3: scanC (inline bsum prefix) || ghist scan + tiles -----
__global__ void k_prep3(const int* __restrict__ gh2, const int* __restrict__ bsum,
                        int* __restrict__ cnt2, int* __restrict__ seg,
                        const int* __restrict__ ghist, int* __restrict__ cnt,
                        int* __restrict__ ntiles_p, int* __restrict__ tile_rel,
                        int* __restrict__ tile_start, int* __restrict__ tile_len) {
    int b = blockIdx.x, t = threadIdx.x;
    if (b < 80) {                                   // scanC
        __shared__ int red[256], spref;
        if (t < 64) {                               // prefix = sum bsum[j<b]
            int v = (t < b) ? bsum[t] : 0;
            if (t < 16 && 64 + t < b) v += bsum[64 + t];
#pragma unroll
            for (int off = 1; off < 64; off <<= 1) v += __shfl_xor(v, off);
            if (t == 0) spref = v;
        }
        int i = b * 256 + t;
        int v = (i < N_NODES) ? gh2[i] : 0;
        red[t] = v;
        __syncthreads();
        for (int off = 1; off < 256; off <<= 1) {
            int x = (t >= off) ? red[t - off] : 0;
            __syncthreads();
            red[t] += x;
            __syncthreads();
        }
        int excl = red[t] - v + spref;
        if (i < N_NODES) {
            cnt2[i] = excl;
            seg[i] = excl;
            if (i == N_NODES - 1) seg[N_NODES] = excl + v;
        }
    } else {                                        // ghist scan + tile descs
        __shared__ int base[R_REL + 1], tbase[R_REL + 1];
        int lane = t & 63;
        if (t < 64) {
            int v = (lane < 64) ? ghist[lane] : 0;
            int x = v;
#pragma unroll
            for (int off = 1; off < 64; off <<= 1) {
                int y = __shfl_up(x, off);
                if (lane >= off) x += y;
            }
            base[lane] = x - v;
            if (lane == 63) {
                base[64] = x;
                base[65] = x + ghist[64];
            }
        }
        __syncthreads();
        if (t == 0) {
            int tb = 0;
            for (int r = 0; r < R_REL; ++r) {
                tbase[r] = tb;
                tb += (base[r + 1] - base[r] + TM - 1) / TM;
            }
            *ntiles_p = tb;
        }
        __syncthreads();
        if (t < R_REL) {
            cnt[t] = base[t];
            int s = base[t], e = base[t + 1], j = tbase[t];
            while (s < e) {
                int len = min(TM, e - s);
                tile_rel[j] = t; tile_start[j] = s; tile_len[j] = len;
                ++j; s += len;
            }
        }
    }
}

// ---------------- K4: rel scatter + dst-position assignment ---------------
__global__ void k_scatter2(const int* __restrict__ et, const int* __restrict__ srcA,
                           const int* __restrict__ dstA, const float* __restrict__ norm,
                           int* __restrict__ cnt, int* __restrict__ cnt2,
                           int* __restrict__ srcp, float* __restrict__ normp,
                           int* __restrict__ inv2) {
    __shared__ int lh[R_REL], lbase[R_REL];
    int c0 = blockIdx.x * SCAT_CH;
    int cend = min(c0 + SCAT_CH, E_EDGES);
    if (threadIdx.x < R_REL) lh[threadIdx.x] = 0;
    __syncthreads();
    for (int i = c0 + threadIdx.x; i < cend; i += 256) atomicAdd(&lh[et[i]], 1);
    __syncthreads();
    if (threadIdx.x < R_REL && lh[threadIdx.x] > 0)
        lbase[threadIdx.x] = atomicAdd(&cnt[threadIdx.x], lh[threadIdx.x]);
    __syncthreads();
    if (threadIdx.x < R_REL) lh[threadIdx.x] = 0;
    __syncthreads();
    for (int i = c0 + threadIdx.x; i < cend; i += 256) {
        int r = et[i];
        int p = lbase[r] + atomicAdd(&lh[r], 1);
        srcp[p] = srcA[i];
        normp[p] = norm[i];
        inv2[p] = atomicAdd(&cnt2[dstA[i]], 1);
    }
}

// ---------------- K5: resid tiles (first 313 blocks) + edge GEMM tiles -----
// r5 conv structure: per-tile block, async16 staging, 1 barrier, NT stores.
__global__ __launch_bounds__(256, 3) void k_conv_gemm(
    const int* __restrict__ tile_rel, const int* __restrict__ tile_start,
    const int* __restrict__ tile_len, const int* __restrict__ ntiles_p,
    const int* __restrict__ srcp, const float* __restrict__ normp,
    const unsigned short* __restrict__ node_bf,
    const unsigned short* __restrict__ Wt, const unsigned short* __restrict__ Wrest,
    const float* __restrict__ b_res, const int* __restrict__ inv2,
    unsigned short* __restrict__ t_out, float* __restrict__ resid) {
    __shared__ unsigned short Alds[64 * 128];
    __shared__ unsigned short Blds[128 * 128];
    __shared__ float snorm[64];
    __shared__ int sp2[64];
    int t = threadIdx.x;
    int w = t >> 6, lane = t & 63;
    int wr = (w >> 1) * 32, wc = (w & 1) * 64;
    int lrow = lane & 15, quad = lane >> 4;

    if (blockIdx.x < NB_RESID) {
        // ---- residual tile: rows row0..row0+63, relu(x@W_res+b) -> resid
        int row0 = blockIdx.x * 64;
        int nrows = min(64, N_NODES - row0);
#pragma unroll
        for (int it = 0; it < 8; ++it) {
            int j = t + 256 * it;
            int o = j >> 4, c = j & 15, cs = c ^ (o & 15);
            async16(Wrest + o * 128 + cs * 8, &Blds[o * 128 + c * 8]);
        }
#pragma unroll
        for (int it = 0; it < 4; ++it) {
            int j = t + 256 * it;
            int p = j >> 4, c = j & 15, cs = c ^ (p & 15);
            if (p < nrows)
                async16(node_bf + (size_t)(row0 + p) * 128 + cs * 8,
                        &Alds[p * 128 + c * 8]);
        }
        __syncthreads();
        f32x4 acc[2][4];
#pragma unroll
        for (int i = 0; i < 2; ++i)
#pragma unroll
            for (int j = 0; j < 4; ++j) acc[i][j] = (f32x4){0.f, 0.f, 0.f, 0.f};
#pragma unroll
        for (int ks = 0; ks < 4; ++ks) {
            int cs = (ks * 4 + quad) ^ lrow;
            bf16x8 af[2], bfr[4];
#pragma unroll
            for (int i = 0; i < 2; ++i)
                af[i] = *reinterpret_cast<const bf16x8*>(&Alds[(wr + i * 16 + lrow) * 128 + cs * 8]);
#pragma unroll
            for (int j = 0; j < 4; ++j)
                bfr[j] = *reinterpret_cast<const bf16x8*>(&Blds[(wc + j * 16 + lrow) * 128 + cs * 8]);
#pragma unroll
            for (int i = 0; i < 2; ++i)
#pragma unroll
                for (int j = 0; j < 4; ++j)
                    acc[i][j] = __builtin_amdgcn_mfma_f32_16x16x32_bf16(af[i], bfr[j], acc[i][j], 0, 0, 0);
        }
        float br0 = b_res[wc + lrow];
        float br1 = b_res[wc + 16 + lrow];
        float br2 = b_res[wc + 32 + lrow];
        float br3 = b_res[wc + 48 + lrow];
#pragma unroll
        for (int i = 0; i < 2; ++i) {
#pragma unroll
            for (int reg = 0; reg < 4; ++reg) {
                int grow = row0 + wr + i * 16 + quad * 4 + reg;
                if (grow < N_NODES) {
                    float4 v;
                    v.x = fmaxf(acc[i][0][reg] + br0, 0.f);
                    v.y = fmaxf(acc[i][1][reg] + br1, 0.f);
                    v.z = fmaxf(acc[i][2][reg] + br2, 0.f);
                    v.w = fmaxf(acc[i][3][reg] + br3, 0.f);
                    *reinterpret_cast<float4*>(resid + (size_t)grow * 128 + wc + lrow * 4) = v;
                }
            }
        }
        return;
    }

    // ---- edge tile (r5 structure)
    int tid = blockIdx.x - NB_RESID;
    if (tid >= *ntiles_p) return;
    int r = tile_rel[tid], start = tile_start[tid], len = tile_len[tid];
    const unsigned short* Wr = Wt + (size_t)r * 16384;
#pragma unroll
    for (int it = 0; it < 8; ++it) {               // stage W (XOR on source)
        int j = t + 256 * it;
        int o = j >> 4, c = j & 15, cs = c ^ (o & 15);
        async16(Wr + o * 128 + cs * 8, &Blds[o * 128 + c * 8]);
    }
#pragma unroll
    for (int it = 0; it < 4; ++it) {               // stage A (gathered rows)
        int j = t + 256 * it;
        int p = j >> 4, c = j & 15, cs = c ^ (p & 15);
        if (p < len)
            async16(node_bf + (size_t)srcp[start + p] * 128 + cs * 8,
                    &Alds[p * 128 + c * 8]);
    }
    if (t < TM && t < len) {
        snorm[t] = normp[start + t];
        sp2[t] = inv2[start + t];
    }
    __syncthreads();

    f32x4 acc[2][4];
#pragma unroll
    for (int i = 0; i < 2; ++i)
#pragma unroll
        for (int j = 0; j < 4; ++j) acc[i][j] = (f32x4){0.f, 0.f, 0.f, 0.f};
#pragma unroll
    for (int ks = 0; ks < 4; ++ks) {
        int cs = (ks * 4 + quad) ^ lrow;
        bf16x8 af[2], bfr[4];
#pragma unroll
        for (int i = 0; i < 2; ++i)
            af[i] = *reinterpret_cast<const bf16x8*>(&Alds[(wr + i * 16 + lrow) * 128 + cs * 8]);
#pragma unroll
        for (int j = 0; j < 4; ++j)
            bfr[j] = *reinterpret_cast<const bf16x8*>(&Blds[(wc + j * 16 + lrow) * 128 + cs * 8]);
#pragma unroll
        for (int i = 0; i < 2; ++i)
#pragma unroll
            for (int j = 0; j < 4; ++j)
                acc[i][j] = __builtin_amdgcn_mfma_f32_16x16x32_bf16(af[i], bfr[j], acc[i][j], 0, 0, 0);
    }

    // epilogue: scale by norm, pack bf16, NT-store permuted row chunk
#pragma unroll
    for (int i = 0; i < 2; ++i) {
        int m0 = wr + i * 16 + quad * 4;
#pragma unroll
        for (int reg = 0; reg < 4; ++reg) {
            int m = m0 + reg;
            if (m < len) {
                float nm = snorm[m];
                int p2 = sp2[m];
                float2 lo2 = make_float2(acc[i][0][reg] * nm, acc[i][1][reg] * nm);
                float2 hi2 = make_float2(acc[i][2][reg] * nm, acc[i][3][reg] * nm);
                __hip_bfloat162 blo = __float22bfloat162_rn(lo2);
                __hip_bfloat162 bhi = __float22bfloat162_rn(hi2);
                u32x2 st;
                st.x = *reinterpret_cast<unsigned int*>(&blo);
                st.y = *reinterpret_cast<unsigned int*>(&bhi);
                __builtin_nontemporal_store(st,
                    reinterpret_cast<u32x2*>(t_out + (size_t)p2 * 128 + wc + lrow * 4));
            }
        }
    }
}

// ---------------- K6: wave-per-dst CSR reduce, 4-deep MLP ------------------
__global__ __launch_bounds__(256) void k_reduce_fused(
    const unsigned short* __restrict__ t, const int* __restrict__ seg,
    const float* __restrict__ resid, const float* __restrict__ h_bias,
    float* __restrict__ h, float* __restrict__ colsum, float* __restrict__ colsumsq) {
    __shared__ float cs1[128], cs2[128], sbias[128];
    if (threadIdx.x < 128) {
        cs1[threadIdx.x] = 0.f; cs2[threadIdx.x] = 0.f;
        sbias[threadIdx.x] = h_bias[unperm(threadIdx.x)];
    }
    __syncthreads();
    int w = threadIdx.x >> 6, lane = threadIdx.x & 63;
    int g = lane >> 4, c = lane & 15;
    for (int k = 0; k < 4; ++k) {
        int d = blockIdx.x * 16 + k * 4 + w;
        int a = seg[d], b = seg[d + 1];
        float s[8];
#pragma unroll
        for (int kk = 0; kk < 8; ++kk) s[kk] = 0.f;
        int q = a + g;
        for (; q + 12 < b; q += 16) {
            u32x4 v0 = __builtin_nontemporal_load(reinterpret_cast<const u32x4*>(t + (size_t)q * 128 + c * 8));
            u32x4 v1 = __builtin_nontemporal_load(reinterpret_cast<const u32x4*>(t + (size_t)(q + 4) * 128 + c * 8));
            u32x4 v2 = __builtin_nontemporal_load(reinterpret_cast<const u32x4*>(t + (size_t)(q + 8) * 128 + c * 8));
            u32x4 v3 = __builtin_nontemporal_load(reinterpret_cast<const u32x4*>(t + (size_t)(q + 12) * 128 + c * 8));
#pragma unroll
            for (int kk = 0; kk < 4; ++kk) {
                s[2 * kk]     += bf2f_lo(v0[kk]) + bf2f_lo(v1[kk]) + bf2f_lo(v2[kk]) + bf2f_lo(v3[kk]);
                s[2 * kk + 1] += bf2f_hi(v0[kk]) + bf2f_hi(v1[kk]) + bf2f_hi(v2[kk]) + bf2f_hi(v3[kk]);
            }
        }
        for (; q < b; q += 4) {
            u32x4 v = __builtin_nontemporal_load(reinterpret_cast<const u32x4*>(t + (size_t)q * 128 + c * 8));
#pragma unroll
            for (int kk = 0; kk < 4; ++kk) {
                s[2 * kk]     += bf2f_lo(v[kk]);
                s[2 * kk + 1] += bf2f_hi(v[kk]);
            }
        }
#pragma unroll
        for (int kk = 0; kk < 8; ++kk) {
            s[kk] += __shfl_xor(s[kk], 16);
            s[kk] += __shfl_xor(s[kk], 32);
        }
        if (g == 0) {
            const float* rp = resid + (size_t)d * 128 + c * 8;
            float4 r0 = *reinterpret_cast<const float4*>(rp);
            float4 r1 = *reinterpret_cast<const float4*>(rp + 4);
            float rr[8] = {r0.x, r0.y, r0.z, r0.w, r1.x, r1.y, r1.z, r1.w};
            float v[8];
#pragma unroll
            for (int kk = 0; kk < 8; ++kk)
                v[kk] = fmaxf(s[kk] + sbias[c * 8 + kk], 0.f) + rr[kk];
            float* hp = h + (size_t)d * 128 + c * 8;
            *reinterpret_cast<float4*>(hp)     = make_float4(v[0], v[1], v[2], v[3]);
            *reinterpret_cast<float4*>(hp + 4) = make_float4(v[4], v[5], v[6], v[7]);
#pragma unroll
            for (int kk = 0; kk < 8; ++kk) {
                atomicAdd(&cs1[c * 8 + kk], v[kk]);
                atomicAdd(&cs2[c * 8 + kk], v[kk] * v[kk]);
            }
        }
    }
    __syncthreads();
    if (threadIdx.x < 128) {
        atomicAdd(&colsum[threadIdx.x], cs1[threadIdx.x]);
        atomicAdd(&colsumsq[threadIdx.x], cs2[threadIdx.x]);
    }
}

// ---------------- K7: BN apply + unpermute to natural cols -----------------
__global__ void k_bn(float* __restrict__ h, const float* __restrict__ colsum,
                     const float* __restrict__ colsumsq, const float* __restrict__ gamma,
                     const float* __restrict__ beta) {
    __shared__ float sc[128], sh[128], tile[8][128];
    int t = threadIdx.x;
    if (t < 128) {
        int n = unperm(t);
        float m = colsum[t] * (1.f / N_NODES);
        float var = colsumsq[t] * (1.f / N_NODES) - m * m;
        float s = gamma[n] * rsqrtf(var + 1e-5f);
        sc[t] = s;
        sh[t] = beta[n] - m * s;
    }
    __syncthreads();
    int r = t >> 5;
    int p0 = (t & 31) * 4;
    int n0 = (p0 & 64) + ((p0 >> 2) & 15);
    for (int row0 = blockIdx.x * 8; row0 < N_NODES; row0 += gridDim.x * 8) {
        int row = row0 + r;
        float4 v = make_float4(0.f, 0.f, 0.f, 0.f);
        if (row < N_NODES) v = *reinterpret_cast<float4*>(h + (size_t)row * 128 + p0);
        v.x = v.x * sc[p0] + sh[p0];
        v.y = v.y * sc[p0 + 1] + sh[p0 + 1];
        v.z = v.z * sc[p0 + 2] + sh[p0 + 2];
        v.w = v.w * sc[p0 + 3] + sh[p0 + 3];
        tile[r][n0]      = v.x;
        tile[r][n0 + 16] = v.y;
        tile[r][n0 + 32] = v.z;
        tile[r][n0 + 48] = v.w;
        __syncthreads();
        if (row < N_NODES)
            *reinterpret_cast<float4*>(h + (size_t)row * 128 + p0) =
                *reinterpret_cast<float4*>(&tile[r][p0]);
        __syncthreads();
    }
}

extern "C" void kernel_launch(void* const* d_in, const int* in_sizes, int n_in,
                              void* d_out, int out_size, void* d_ws, size_t ws_size,
                              hipStream_t stream) {
    (void)in_sizes; (void)n_in; (void)out_size; (void)ws_size;
    const float* node_feats = (const float*)d_in[0];
    const int* src    = (const int*)d_in[1];
    const int* dst    = (const int*)d_in[2];
    const int* etype  = (const int*)d_in[3];
    const float* norm = (const float*)d_in[4];
    const float* basis = (const float*)d_in[5];
    const float* comp  = (const float*)d_in[6];
    const float* h_bias = (const float*)d_in[7];
    const float* W_res  = (const float*)d_in[8];
    const float* b_res  = (const float*)d_in[9];
    const float* gamma  = (const float*)d_in[10];
    const float* beta   = (const float*)d_in[11];

    char* ws = (char*)d_ws;
    // ctrl block (zeroed by one 88KB memset together with gh2)
    int* ghist      = (int*)(ws + 0);          // 260B
    int* cnt        = (int*)(ws + 1024);
    int* ntiles_p   = (int*)(ws + 2048);
    float* colsum   = (float*)(ws + 2560);
    float* colsumsq = (float*)(ws + 3072);
    int* bsum       = (int*)(ws + 3584);       // 320B
    int* gh2        = (int*)(ws + 8192);       // 80000 -> 88192
    int* tile_rel   = (int*)(ws + 88192);      // 40960
    int* tile_start = (int*)(ws + 129152);     // 40960
    int* tile_len   = (int*)(ws + 170112);     // 40960 -> 211072
    unsigned short* Wt      = (unsigned short*)(ws + 211072);    // 2129920 -> 2340992
    unsigned short* Wrest   = (unsigned short*)(ws + 2340992);   // 32768   -> 2373760
    unsigned short* node_bf = (unsigned short*)(ws + 2373760);   // 5120000 -> 7493760
    int* srcp       = (int*)(ws + 7493760);    // 2560000 -> 10053760
    float* normp    = (float*)(ws + 10053760); // 2560000 -> 12613760
    int* inv2       = (int*)(ws + 12613760);   // 2560000 -> 15173760
    float* resid    = (float*)(ws + 15173760); // 10240000 -> 25413760
    int* seg        = (int*)(ws + 25413760);   // 80004 -> 25493764, pad
    int* cnt2       = (int*)(ws + 25493776);   // 80000 -> 25573776
    const long T_BASE = 25573776L;             // 16B aligned
    float* W32      = (float*)(ws + T_BASE);   // aliased: dead before conv
    unsigned short* t_buf = (unsigned short*)(ws + T_BASE);      // 163.84 MB
    float* hacc = (float*)d_out;

    hipMemsetAsync(ws, 0, 88192, stream);
    k_prep1<<<3332, 256, 0, stream>>>(comp, basis, W32, etype, dst, ghist, gh2,
                                      node_feats, node_bf);
    k_prep2<<<344, 256, 0, stream>>>(W32, Wt, W_res, Wrest, gh2, bsum);
    k_prep3<<<81, 256, 0, stream>>>(gh2, bsum, cnt2, seg, ghist, cnt, ntiles_p,
                                    tile_rel, tile_start, tile_len);
    k_scatter2<<<(E_EDGES + SCAT_CH - 1) / SCAT_CH, 256, 0, stream>>>(
        etype, src, dst, norm, cnt, cnt2, srcp, normp, inv2);
    k_conv_gemm<<<NB_RESID + MAX_TILES, 256, 0, stream>>>(
        tile_rel, tile_start, tile_len, ntiles_p, srcp, normp, node_bf,
        Wt, Wrest, b_res, inv2, t_buf, resid);
    k_reduce_fused<<<N_NODES / 16, 256, 0, stream>>>(t_buf, seg, resid, h_bias,
                                                     hacc, colsum, colsumsq);
    k_bn<<<2500, 256, 0, stream>>>(hacc, colsum, colsumsq, gamma, beta);
}